// Round 27
// baseline (164.025 us; speedup 1.0000x reference)
//
#include <hip/hip_runtime.h>
#include <hip/hip_bf16.h>

// GraphAttentionLayer: B=8,N=1024,FIN=E=OUT=128,NH=8,HD=16. f32 in/out.
// R27 = R25 verbatim (best passing: 161.9us, absmax 9.2e-5, 4 dispatches).
// R26's cooperative mega-kernel silently failed AGAIN (19.2KB LDS, so the
// R8 LDS-size theory is dead): hipLaunchCooperativeKernel does not survive
// this harness's graph capture. Cooperative path permanently closed.
// Ledger: R25 structure = prep+hp merged / qkvz merged / MFMA flash
// (2 heads/block, bank-safe strides) / MFMA out. Do not touch flash/qkvz
// (codegen-chaos risk, R13-R17).

using u16 = unsigned short;
typedef short bf16x8 __attribute__((ext_vector_type(8)));
typedef float f32x4 __attribute__((ext_vector_type(4)));
typedef _Float16 f16;
typedef _Float16 f16x4 __attribute__((ext_vector_type(4)));

#define MFMA16(a, b, c) __builtin_amdgcn_mfma_f32_16x16x16f16(a, b, c, 0, 0, 0)

__device__ __forceinline__ u16 f2b(float f) {
    unsigned u = __float_as_uint(f);
    return (u16)((u + 0x7fffu + ((u >> 16) & 1u)) >> 16);  // RNE
}
__device__ __forceinline__ float b2f(u16 u) {
    return __uint_as_float(((unsigned)u) << 16);
}

// ---- merged prep + Hp-GEMM ----
__global__ void prep_hp(const float* __restrict__ H, const float* __restrict__ Wlin,
                        const float* __restrict__ Win,
                        const float* __restrict__ Wout, const float* __restrict__ Wfin,
                        const float* __restrict__ bout, const float* __restrict__ bfin,
                        const float* __restrict__ blin, const float* __restrict__ Aadj,
                        u16* __restrict__ WinTb, u16* __restrict__ WcombTb,
                        float* __restrict__ bcomb, float* __restrict__ rowsum,
                        unsigned char* __restrict__ A8, u16* __restrict__ Hpb) {
    if (blockIdx.x < 64) {
        const int m0 = blockIdx.x * 128;
        const int t = threadIdx.x;
        const int wave = t >> 6, lane = t & 63;
        const int wm = (wave >> 1) * 64, wn = (wave & 1) * 64;
        const int m16 = lane & 15, kq = lane >> 4;
        f32x4 acc[4][4] = {};

#pragma unroll
        for (int kc = 0; kc < 4; ++kc) {
            bf16x8 af[4], bf[4];
#pragma unroll
            for (int i = 0; i < 4; ++i) {
                const float* ap = &H[(long long)(m0 + wm + i * 16 + m16) * 128 + kc * 32 + kq * 8];
                float4 u0 = *(const float4*)ap;
                float4 u1 = *(const float4*)(ap + 4);
                bf16x8 a;
                a[0] = (short)f2b(u0.x); a[1] = (short)f2b(u0.y);
                a[2] = (short)f2b(u0.z); a[3] = (short)f2b(u0.w);
                a[4] = (short)f2b(u1.x); a[5] = (short)f2b(u1.y);
                a[6] = (short)f2b(u1.z); a[7] = (short)f2b(u1.w);
                af[i] = a;
            }
#pragma unroll
            for (int j = 0; j < 4; ++j) {
                const int col = wn + j * 16 + m16;
                const int k0 = kc * 32 + kq * 8;
                bf16x8 bb;
#pragma unroll
                for (int e = 0; e < 8; ++e)
                    bb[e] = (short)f2b(Wlin[(long long)(k0 + e) * 128 + col]);
                bf[j] = bb;
            }
#pragma unroll
            for (int i = 0; i < 4; ++i)
#pragma unroll
                for (int j = 0; j < 4; ++j)
                    acc[i][j] = __builtin_amdgcn_mfma_f32_16x16x32_bf16(af[i], bf[j], acc[i][j], 0, 0, 0);
        }
#pragma unroll
        for (int i = 0; i < 4; ++i) {
#pragma unroll
            for (int r = 0; r < 4; ++r) {
                long long row = m0 + wm + i * 16 + kq * 4 + r;
#pragma unroll
                for (int j = 0; j < 4; ++j) {
                    int col = wn + j * 16 + m16;
                    Hpb[row * 128 + col] = f2b(acc[i][j][r] + blin[col]);
                }
            }
        }
        return;
    }
    int i = (blockIdx.x - 64) * 256 + threadIdx.x;   // 0..1130495
    if (i >= 81920) {
        int j = i - 81920;                    // 0..1048575: pack 8 elems each
        long long base = (long long)j * 8;
        float4 a0 = *(const float4*)&Aadj[base];
        float4 a1 = *(const float4*)&Aadj[base + 4];
        unsigned long long m = 0;
        m |= (unsigned long long)(a0.x != 0.f) << 0;
        m |= (unsigned long long)(a0.y != 0.f) << 8;
        m |= (unsigned long long)(a0.z != 0.f) << 16;
        m |= (unsigned long long)(a0.w != 0.f) << 24;
        m |= (unsigned long long)(a1.x != 0.f) << 32;
        m |= (unsigned long long)(a1.y != 0.f) << 40;
        m |= (unsigned long long)(a1.z != 0.f) << 48;
        m |= (unsigned long long)(a1.w != 0.f) << 56;
        *(unsigned long long*)&A8[base] = m;
        return;
    }
    if (i < 8192) rowsum[i] = 0.f;
    if (i >= 16384 && i < 65536) {
        int k = i - 16384;                    // Win 128x384 -> WinTb 384x128 bf16
        int r = k / 384, c = k - r * 384;
        WinTb[c * 128 + r] = f2b(Win[k]);
    } else if (i >= 65536) {
        int k = i - 65536;
        int o = k & 127, e = k >> 7;          // o fastest: Wfin coalesced
        float s = 0.f;
        for (int kk = 0; kk < 128; ++kk)
            s = fmaf(Wout[e * 128 + kk], Wfin[kk * 128 + o], s);
        WcombTb[o * 128 + e] = f2b(s);
        if (e == 0) {
            float sb = bfin[o];
            for (int kk = 0; kk < 128; ++kk)
                sb = fmaf(bout[kk], Wfin[kk * 128 + o], sb);
            bcomb[o] = sb;
        }
    }
}

// ---- merged: blk<512 -> ez = bf16(exp(lrelu(Hpb@Hpb^T)*A8)) + exp-rowsum;
//      blk>=512 -> qkv (all f16: q*0.25 | k | v, 384 halves/row) ----
__global__ __launch_bounds__(256)
void mfma_qkvz(const u16* __restrict__ Hpb, const u16* __restrict__ WinTb,
               const float* __restrict__ bin, f16* __restrict__ Cq,
               const unsigned char* __restrict__ G8, u16* __restrict__ EZ,
               float* __restrict__ rowsum) {
    const int blk = blockIdx.x;
    const int t = threadIdx.x;
    const int wave = t >> 6, lane = t & 63;
    const int wm = (wave >> 1) * 64, wn = (wave & 1) * 64;
    const int m16 = lane & 15, kq = lane >> 4;
    f32x4 acc[4][4] = {};

    if (blk < 512) {
        const int b = blk >> 6, mt = (blk >> 3) & 7, nt = blk & 7;
        const u16* Ab = Hpb + (long long)b * 1024 * 128;
        const int m0 = mt * 128, n0 = nt * 128;
#pragma unroll
        for (int kc = 0; kc < 4; ++kc) {
            bf16x8 af[4], bf[4];
#pragma unroll
            for (int i = 0; i < 4; ++i)
                af[i] = *(const bf16x8*)&Ab[(long long)(m0 + wm + i * 16 + m16) * 128 + kc * 32 + kq * 8];
#pragma unroll
            for (int j = 0; j < 4; ++j)
                bf[j] = *(const bf16x8*)&Ab[(long long)(n0 + wn + j * 16 + m16) * 128 + kc * 32 + kq * 8];
#pragma unroll
            for (int i = 0; i < 4; ++i)
#pragma unroll
                for (int j = 0; j < 4; ++j)
                    acc[i][j] = __builtin_amdgcn_mfma_f32_16x16x32_bf16(af[i], bf[j], acc[i][j], 0, 0, 0);
        }
        const long long zb = (long long)b * 1024 * 1024;
#pragma unroll
        for (int i = 0; i < 4; ++i) {
#pragma unroll
            for (int r = 0; r < 4; ++r) {
                int row = m0 + wm + i * 16 + kq * 4 + r;
                float es = 0.f;
#pragma unroll
                for (int j = 0; j < 4; ++j) {
                    int col = n0 + wn + j * 16 + m16;
                    float v = acc[i][j][r];
                    v = v >= 0.f ? v : 0.2f * v;                  // LeakyReLU(0.2)
                    if (!G8[zb + (long long)row * 1024 + col]) v = 0.f;  // binary gate
                    float ev = __expf(v);                         // m=0: |z| bounded
                    EZ[zb + (long long)row * 1024 + col] = f2b(ev);
                    es += ev;
                }
#pragma unroll
                for (int off = 1; off < 16; off <<= 1) es += __shfl_xor(es, off);
                if (m16 == 0) atomicAdd(&rowsum[b * 1024 + row], es);
            }
        }
    } else {
        const int q = blk - 512;
        const int mt = q & 63, slab = q >> 6;   // 0=q, 1=k, 2=v
        const int m0 = mt * 128;
        const u16* Bslab = WinTb + (long long)slab * 128 * 128;
#pragma unroll
        for (int kc = 0; kc < 4; ++kc) {
            bf16x8 af[4], bf[4];
#pragma unroll
            for (int i = 0; i < 4; ++i)
                af[i] = *(const bf16x8*)&Hpb[(long long)(m0 + wm + i * 16 + m16) * 128 + kc * 32 + kq * 8];
#pragma unroll
            for (int j = 0; j < 4; ++j)
                bf[j] = *(const bf16x8*)&Bslab[(long long)(wn + j * 16 + m16) * 128 + kc * 32 + kq * 8];
#pragma unroll
            for (int i = 0; i < 4; ++i)
#pragma unroll
                for (int j = 0; j < 4; ++j)
                    acc[i][j] = __builtin_amdgcn_mfma_f32_16x16x32_bf16(af[i], bf[j], acc[i][j], 0, 0, 0);
        }
        const float qscale = (slab == 0) ? 0.25f : 1.f;   // fold 1/sqrt(HD) into q
#pragma unroll
        for (int i = 0; i < 4; ++i) {
#pragma unroll
            for (int r = 0; r < 4; ++r) {
                long long row = m0 + wm + i * 16 + kq * 4 + r;
#pragma unroll
                for (int j = 0; j < 4; ++j) {
                    int col = wn + j * 16 + m16;
                    float v = (acc[i][j][r] + bin[slab * 128 + col]) * qscale;
                    Cq[row * 384 + slab * 128 + col] = (f16)v;
                }
            }
        }
    }
}

// ---- flash (MFMA): block = (b, 64 qrows, 2 heads), full K. 256 thr.
// grid (16,8,4) = 512 blocks -> 2 blk/CU. Byte-identical to R23/R24/R25.
__global__ __launch_bounds__(256)
void flash_mfma(const f16* __restrict__ qkv, const u16* __restrict__ ez,
                const float* __restrict__ rowsum, float* __restrict__ o_) {
    const int n0 = blockIdx.x * 64;
    const int b = blockIdx.y;
    const int h0 = blockIdx.z * 2;       // 2 heads per block
    const int t = threadIdx.x;
    const int w = t >> 6, lane = t & 63;
    const int qr16 = lane & 15, quad = lane >> 4;

    __shared__ u16 Ks[64 * 40];    // [key][dim 0..31 of head pair], stride 40
    __shared__ u16 VTs[32 * 76];   // [dim 0..31][key], stride 76 (bank-safe)
    __shared__ u16 AWs[64 * 72];   // [qrow 0..63][key 0..63] bf16 (ez)

    const int qrow_l = w * 16 + qr16;                 // block-local qrow
    const long long qrow_g = b * 1024 + n0 + qrow_l;  // global qrow
    const float inv0 = 1.f / rowsum[qrow_g];

    f16x4 qf[2];
#pragma unroll
    for (int hh = 0; hh < 2; ++hh)
        qf[hh] = *(const f16x4*)&qkv[qrow_g * 384 + (h0 + hh) * 16 + quad * 4];

    f32x4 accO[2] = {};
    float lacc[2] = {0.f, 0.f};

    for (int st = 0; st < 16; ++st) {
        const int kb = st * 64;
        __syncthreads();
        // stage K (64 keys x 32 dims) b128: key = t>>2, c8 = t&3
        {
            const int key = t >> 2, c8 = t & 3;
            *(uint4*)&Ks[key * 40 + c8 * 8] =
                *(const uint4*)&qkv[((long long)(b * 1024 + kb + key)) * 384 + 128 + h0 * 16 + c8 * 8];
            // stage V transposed: VTs[dim][key]; write bank-step 16 -> <=2-way
            const f16* vsrc = &qkv[((long long)(b * 1024 + kb + key)) * 384 + 256 + h0 * 16 + c8 * 8];
            f16x4 v0 = *(const f16x4*)vsrc;
            f16x4 v1 = *(const f16x4*)(vsrc + 4);
            const int d0 = c8 * 8;
#pragma unroll
            for (int i = 0; i < 4; ++i) {
                VTs[(d0 + i) * 76 + key] = ((const u16*)&v0)[i];
                VTs[(d0 + 4 + i) * 76 + key] = ((const u16*)&v1)[i];
            }
        }
        // stage AW (64 qrows x 64 keys) b128
#pragma unroll
        for (int rr = 0; rr < 2; ++rr) {
            int idx = rr * 256 + t;
            int row = idx >> 3, c16 = idx & 7;
            *(uint4*)&AWs[row * 72 + c16 * 8] =
                *(const uint4*)&ez[((long long)(b * 1024 + n0 + row)) * 1024 + kb + c16 * 8];
        }
        __syncthreads();

#pragma unroll 2
        for (int kt = 0; kt < 4; ++kt) {
            // aw C-init: lane holds (qrow=qr16, keys kt*16+quad*4+r)
            ushort4 ue = *(const ushort4*)&AWs[qrow_l * 72 + kt * 16 + quad * 4];
            f32x4 aw0;
            aw0[0] = b2f(ue.x) * inv0; aw0[1] = b2f(ue.y) * inv0;
            aw0[2] = b2f(ue.z) * inv0; aw0[3] = b2f(ue.w) * inv0;
#pragma unroll
            for (int hh = 0; hh < 2; ++hh) {
                f16x4 kf = *(const f16x4*)&Ks[(kt * 16 + qr16) * 40 + hh * 16 + quad * 4];
                f32x4 s4 = MFMA16(kf, qf[hh], aw0);
                float p0 = __expf(s4[0]), p1 = __expf(s4[1]);
                float p2 = __expf(s4[2]), p3 = __expf(s4[3]);
                lacc[hh] += (p0 + p1) + (p2 + p3);
                f16x4 pf;
                pf[0] = (f16)p0; pf[1] = (f16)p1; pf[2] = (f16)p2; pf[3] = (f16)p3;
                f16x4 vf = *(const f16x4*)&VTs[(hh * 16 + qr16) * 76 + kt * 16 + quad * 4];
                accO[hh] = MFMA16(vf, pf, accO[hh]);
            }
        }
    }
    // finalize: l over quads (lanes sharing qr16), then store o normalized
#pragma unroll
    for (int hh = 0; hh < 2; ++hh) {
        float l = lacc[hh];
        l += __shfl_xor(l, 16);
        l += __shfl_xor(l, 32);
        float inv = 1.f / l;
        float* orow = o_ + qrow_g * 128 + (h0 + hh) * 16 + quad * 4;
#pragma unroll
        for (int r = 0; r < 4; ++r) orow[r] = accO[hh][r] * inv;
    }
}

// -------- out = cast(o_) @ WcombTb^T + bcomb : MFMA, 128-row blocks --------
__global__ __launch_bounds__(256)
void mfma_out(const float* __restrict__ A, const u16* __restrict__ Bb,
              const float* __restrict__ bias, float* __restrict__ C) {
    const int m0 = blockIdx.x * 128;
    const int t = threadIdx.x;
    const int wave = t >> 6, lane = t & 63;
    const int wm = (wave >> 1) * 64, wn = (wave & 1) * 64;
    const int m16 = lane & 15, kq = lane >> 4;
    f32x4 acc[4][4] = {};

#pragma unroll
    for (int kc = 0; kc < 4; ++kc) {
        bf16x8 af[4], bf[4];
#pragma unroll
        for (int i = 0; i < 4; ++i) {
            const float* ap = &A[(long long)(m0 + wm + i * 16 + m16) * 128 + kc * 32 + kq * 8];
            float4 u0 = *(const float4*)ap;
            float4 u1 = *(const float4*)(ap + 4);
            bf16x8 a;
            a[0] = (short)f2b(u0.x); a[1] = (short)f2b(u0.y);
            a[2] = (short)f2b(u0.z); a[3] = (short)f2b(u0.w);
            a[4] = (short)f2b(u1.x); a[5] = (short)f2b(u1.y);
            a[6] = (short)f2b(u1.z); a[7] = (short)f2b(u1.w);
            af[i] = a;
        }
#pragma unroll
        for (int j = 0; j < 4; ++j)
            bf[j] = *(const bf16x8*)&Bb[(long long)(wn + j * 16 + m16) * 128 + kc * 32 + kq * 8];
#pragma unroll
        for (int i = 0; i < 4; ++i)
#pragma unroll
            for (int j = 0; j < 4; ++j)
                acc[i][j] = __builtin_amdgcn_mfma_f32_16x16x32_bf16(af[i], bf[j], acc[i][j], 0, 0, 0);
    }
#pragma unroll
    for (int i = 0; i < 4; ++i) {
#pragma unroll
        for (int r = 0; r < 4; ++r) {
            long long row = m0 + wm + i * 16 + kq * 4 + r;
#pragma unroll
            for (int j = 0; j < 4; ++j) {
                int col = wn + j * 16 + m16;
                C[row * 128 + col] = acc[i][j][r] + bias[col];
            }
        }
    }
}

extern "C" void kernel_launch(void* const* d_in, const int* in_sizes, int n_in,
                              void* d_out, int out_size, void* d_ws, size_t ws_size,
                              hipStream_t stream) {
    (void)in_sizes; (void)n_in; (void)out_size; (void)ws_size;
    const float* H    = (const float*)d_in[0];
    const float* Aadj = (const float*)d_in[1];
    const float* Wlin = (const float*)d_in[2];
    const float* blin = (const float*)d_in[3];
    const float* Win  = (const float*)d_in[4];
    const float* bin  = (const float*)d_in[5];
    const float* Wout = (const float*)d_in[6];
    const float* bout = (const float*)d_in[7];
    const float* Wfin = (const float*)d_in[8];
    const float* bfin = (const float*)d_in[9];
    float* out = (float*)d_out;
    char* ws = (char*)d_ws;

    u16*   WinTb   = (u16*)(ws + 0);          // 96 KB bf16
    u16*   WcombTb = (u16*)(ws + 98304);      // 32 KB bf16
    float* bcomb   = (float*)(ws + 131072);   // 512 B
    float* rowsum  = (float*)(ws + 131584);   // 32 KB
    u16*   Hpb     = (u16*)(ws + 262144);     // 2 MB bf16
    f16*   qkv     = (f16*)(ws + 2359296);    // 6 MB (q f16*0.25 | k f16 | v f16)
    float* o_      = (float*)(ws + 8650752);  // 4 MB
    u16*   ez      = (u16*)(ws + 12845056);   // 16 MB bf16 exp(z)
    unsigned char* A8 = (unsigned char*)(ws + 29622272);  // 8.4 MB u8 gate
    // total ~38 MB

    // merged prep (4416 blocks) + Hp MFMA (64 blocks)
    prep_hp<<<4480, 256, 0, stream>>>(H, Wlin, Win, Wout, Wfin, bout, bfin,
                                      blin, Aadj, WinTb, WcombTb, bcomb,
                                      rowsum, A8, Hpb);
    // merged: ez-gate (512 blocks, u8 gate) + qkv f16 (192 blocks)
    mfma_qkvz<<<704, 256, 0, stream>>>(Hpb, WinTb, bin, qkv, A8, ez, rowsum);
    // flash (MFMA, full-K blocks, 2 heads/block, no partials)
    flash_mfma<<<dim3(16, 8, 4), 256, 0, stream>>>(qkv, ez, rowsum, o_);
    // out = cast(o_) @ WcombTb^T + bcomb  (MFMA)
    mfma_out<<<64, 256, 0, stream>>>(o_, WcombTb, bcomb, out);
}